// Round 19
// baseline (241.823 us; speedup 1.0000x reference)
//
#include <hip/hip_runtime.h>
#include <hip/hip_bf16.h>

#define DEV __device__ __forceinline__

typedef __attribute__((ext_vector_type(8))) short bf8;    // 8 x bf16 (4 VGPRs)
typedef __attribute__((ext_vector_type(4))) float f4;     // 16x16 MFMA acc
typedef __attribute__((ext_vector_type(16))) float f16x;  // 32x32 MFMA acc

#define GLOAD_LDS(gp, lp) \
  __builtin_amdgcn_global_load_lds( \
      (const __attribute__((address_space(1))) void*)(gp), \
      (__attribute__((address_space(3))) void*)(lp), 16, 0, 0)

DEV unsigned short f2bf(float f) {
  union { __hip_bfloat16 h; unsigned short u; } c;
  c.h = __float2bfloat16(f);
  return c.u;
}
DEV unsigned int pk2(float a, float b) {
  union { __hip_bfloat162 h; unsigned int u; } c;
  c.h = __hip_bfloat162(__float2bfloat16(a), __float2bfloat16(b));
  return c.u;
}

// XCD-aware bijective block swizzle + 4-wide N supertiling.
DEV int2 swz_tile(int ob, int nxt, int nyt) {
  const int nb = nxt * nyt;
  const int cpx = nb >> 3;
  const int W = (ob & 7) * cpx + (ob >> 3);
  const int scw = 4 * nyt;
  const int sc = W / scw, rem = W - sc * scw;
  return make_int2(rem >> 2, sc * 4 + (rem & 3));
}

// ---------------------------------------------------------------------------
// 128x128-tile GEMM (QKV / FFN1) — m97-structure: 256 thr = 4 waves (2x2),
// per-wave 64x64 out (4x4 frags), BK=32, 2 LDS slots (32 KB) -> 3-4 blocks/CU.
// 2-phase double-buffer, 1 barrier/K-tile, XCD-swizzled 1D grid.
// WRVT: cols >= 2048 (V of QKV) written transposed to vtout [b*16+h][64][2048].
// ---------------------------------------------------------------------------
template<bool BIAS, bool RELU, bool RESID, bool OUTBF, bool WRVT>
__global__ __launch_bounds__(256) void gemm_bt128(
    const unsigned short* __restrict__ A, const unsigned short* __restrict__ B,
    const float* __restrict__ bias, const float* __restrict__ resid,
    void* __restrict__ Cout, int M, int N, int K, int ldc,
    unsigned short* __restrict__ vtout, int nyt)
{
  __shared__ unsigned short Al[2][128 * 32];
  __shared__ unsigned short Bl[2][128 * 32];
  const int t = threadIdx.x;
  const int w = t >> 6, l = t & 63;
  const int wr = w >> 1, wc = w & 1;
  int2 tt = swz_tile((int)blockIdx.x, N >> 7, nyt);
  const int m0 = tt.x * 128, n0 = tt.y * 128;

  const int srow = w * 16 + (l >> 2);                         // + i*64
  const int scsw = ((l & 3) * 8) ^ (((srow >> 1) & 3) << 3);  // pre-swizzled col
  const unsigned short* Ab = A + (size_t)(m0 + srow) * K + scsw;
  const unsigned short* Bb = B + (size_t)(n0 + srow) * K + scsw;
  const int sdst = w * 512 + l * 8;                           // + i*2048

  auto STAGE = [&](int slot, int k0) {
#pragma unroll
    for (int i = 0; i < 2; ++i) {
      GLOAD_LDS(Ab + (size_t)i * 64 * K + k0, &Al[slot][sdst + i * 2048]);
      GLOAD_LDS(Bb + (size_t)i * 64 * K + k0, &Bl[slot][sdst + i * 2048]);
    }
  };

  const f4 fz = {0.f, 0.f, 0.f, 0.f};
  f4 acc[4][4];
#pragma unroll
  for (int i = 0; i < 4; ++i)
#pragma unroll
    for (int j = 0; j < 4; ++j) acc[i][j] = fz;

  const int NT = K >> 5;
  STAGE(0, 0);
  __syncthreads();

  for (int T = 0; T < NT; ++T) {
    if (T + 1 < NT) STAGE((T + 1) & 1, (T + 1) * 32);
    const int sl = T & 1;
    const int rdcol = ((l >> 4) * 8) ^ ((((l & 15) >> 1) & 3) << 3);
    bf8 af[4], bg[4];
#pragma unroll
    for (int am = 0; am < 4; ++am)
      af[am] = *(const bf8*)&Al[sl][(wr * 64 + am * 16 + (l & 15)) * 32 + rdcol];
#pragma unroll
    for (int bn = 0; bn < 4; ++bn)
      bg[bn] = *(const bf8*)&Bl[sl][(wc * 64 + bn * 16 + (l & 15)) * 32 + rdcol];
    __builtin_amdgcn_s_setprio(1);
#pragma unroll
    for (int am = 0; am < 4; ++am)
#pragma unroll
      for (int bn = 0; bn < 4; ++bn)
        acc[am][bn] = __builtin_amdgcn_mfma_f32_16x16x32_bf16(af[am], bg[bn], acc[am][bn], 0, 0, 0);
    __builtin_amdgcn_s_setprio(0);
    __syncthreads();
  }

#pragma unroll
  for (int bn = 0; bn < 4; ++bn) {
    const int col = n0 + wc * 64 + bn * 16 + (l & 15);
    float bv = 0.f;
    if (BIAS) bv = bias[col];
    const bool isv = WRVT && (col >= 2048);
    const int hh = (col - 2048) >> 6, dd = (col - 2048) & 63;
#pragma unroll
    for (int am = 0; am < 4; ++am) {
#pragma unroll
      for (int r = 0; r < 4; ++r) {
        const int row = m0 + wr * 64 + am * 16 + ((l >> 4) * 4) + r;
        float v = acc[am][bn][r] + bv;
        if (RELU) v = fmaxf(v, 0.f);
        if (RESID) v += resid[(size_t)row * ldc + col];
        if (WRVT && isv) {
          const int bb = row >> 11, ss = row & 2047;
          vtout[((size_t)(bb * 16 + hh) * 64 + dd) * 2048 + ss] = f2bf(v);
        } else if (OUTBF) {
          ((unsigned short*)Cout)[(size_t)row * ldc + col] = f2bf(v);
        } else {
          ((float*)Cout)[(size_t)row * ldc + col] = v;
        }
      }
    }
  }
}

// ---------------------------------------------------------------------------
// 64x128-tile GEMM, BK=64 (WO / FFN2): 2 LDS slots (48 KB), 2-phase
// double-buffer, 1 barrier/K-tile. 256 thr = 4 waves (2x2); per-wave 32x64.
// ---------------------------------------------------------------------------
template<bool BIAS, bool RELU, bool RESID, bool OUTBF>
__global__ __launch_bounds__(256) void gemm_bt64(
    const unsigned short* __restrict__ A, const unsigned short* __restrict__ B,
    const float* __restrict__ bias, const float* __restrict__ resid,
    void* __restrict__ Cout, int M, int N, int K, int ldc)
{
  __shared__ unsigned short Al[2][64 * 64];
  __shared__ unsigned short Bl[2][128 * 64];
  const int t = threadIdx.x;
  const int w = t >> 6, l = t & 63;
  const int wr = w >> 1, wc = w & 1;
  int2 tt = swz_tile((int)blockIdx.x, N >> 7, M >> 6);
  const int m0 = tt.x * 64, n0 = tt.y * 128;

  const int srow = t >> 3;                        // 0..31
  const int scol = 8 * ((t & 7) ^ (srow & 7));    // pre-swizzled elem col
  const unsigned short* Ab = A + (size_t)(m0 + srow) * K + scol;
  const unsigned short* Bb = B + (size_t)(n0 + srow) * K + scol;
  const int sdst = srow * 64 + (t & 7) * 8;

  auto STAGE = [&](int slot, int k0) {
#pragma unroll
    for (int i = 0; i < 2; ++i)
      GLOAD_LDS(Ab + (size_t)(i * 32) * K + k0, &Al[slot][sdst + i * 32 * 64]);
#pragma unroll
    for (int i = 0; i < 4; ++i)
      GLOAD_LDS(Bb + (size_t)(i * 32) * K + k0, &Bl[slot][sdst + i * 32 * 64]);
  };

  const f4 fz = {0.f, 0.f, 0.f, 0.f};
  f4 acc[2][4];
#pragma unroll
  for (int i = 0; i < 2; ++i)
#pragma unroll
    for (int j = 0; j < 4; ++j) acc[i][j] = fz;

  const int NT = K >> 6;
  STAGE(0, 0);
  __syncthreads();

  for (int T = 0; T < NT; ++T) {
    if (T + 1 < NT) STAGE((T + 1) & 1, (T + 1) * 64);
    const int sl = T & 1;
#pragma unroll
    for (int ks = 0; ks < 2; ++ks) {
      const int cb = (ks * 64 + ((l >> 4) * 16)) ^ ((l & 7) << 4);
      bf8 af[2], bg[4];
#pragma unroll
      for (int am = 0; am < 2; ++am)
        af[am] = *(const bf8*)((const char*)&Al[sl][(wr * 32 + am * 16 + (l & 15)) * 64] + cb);
#pragma unroll
      for (int bn = 0; bn < 4; ++bn)
        bg[bn] = *(const bf8*)((const char*)&Bl[sl][(wc * 64 + bn * 16 + (l & 15)) * 64] + cb);
      __builtin_amdgcn_s_setprio(1);
#pragma unroll
      for (int am = 0; am < 2; ++am)
#pragma unroll
        for (int bn = 0; bn < 4; ++bn)
          acc[am][bn] = __builtin_amdgcn_mfma_f32_16x16x32_bf16(af[am], bg[bn], acc[am][bn], 0, 0, 0);
      __builtin_amdgcn_s_setprio(0);
    }
    __syncthreads();
  }

#pragma unroll
  for (int bn = 0; bn < 4; ++bn) {
    const int col = n0 + wc * 64 + bn * 16 + (l & 15);
    float bv = 0.f;
    if (BIAS) bv = bias[col];
#pragma unroll
    for (int am = 0; am < 2; ++am) {
#pragma unroll
      for (int r = 0; r < 4; ++r) {
        const int row = m0 + wr * 32 + am * 16 + ((l >> 4) * 4) + r;
        float v = acc[am][bn][r] + bv;
        if (RELU) v = fmaxf(v, 0.f);
        if (RESID) v += resid[(size_t)row * ldc + col];
        if (OUTBF) ((unsigned short*)Cout)[(size_t)row * ldc + col] = f2bf(v);
        else       ((float*)Cout)[(size_t)row * ldc + col] = v;
      }
    }
  }
}

// ---------------------------------------------------------------------------
// Causal flash attention — split-KV, fixed-scale softmax, DOUBLE-BUFFERED K/V
// (R7/bt128 staging discipline): prefetch tile it+1 into buf^1 before
// computing buf; ONE barrier per iteration. KV is XCD-pinned L2-resident
// (~200 cyc latency < ~600 cyc compute phase), so the barrier's vmcnt drain
// finds loads already returned -> exposed latency ~0 (vs full drain before).
// LDS 64 KB -> 2 blocks/CU; latency now hidden in-block, not cross-block.
// ---------------------------------------------------------------------------
__global__ __launch_bounds__(256, 2) void attn_kernel(
    const unsigned short* __restrict__ qk, const unsigned short* __restrict__ vt,
    unsigned short* __restrict__ ctx)
{
  __shared__ unsigned short SM[2][2][2][64 * 64]; // [pair][buf][K=0/V=1][...]

  const int t = threadIdx.x;
  const int w = t >> 6, l = t & 63;
  const int p = w >> 1;                 // KV half
  const int hi = l >> 5, q = l & 31;
  const int bid = blockIdx.x;
  const int xcd = bid & 7, i = bid >> 3;
  const int g = i >> 5, c = i & 31;
  const int s = (g & 1) ? c : 31 - c;         // anti-correlated CU load
  const int bh = xcd * 4 + g;                 // 4 (b,h) pairs per XCD
  const int b = bh >> 4, h = bh & 15;
  const int tile = 2 * s + (w & 1);
  const int q0w = tile * 32;
  const int h0 = (s + 2) >> 1;                // pair0 iters; pair1 = s+1-h0

  const unsigned short* qbase = qk + ((size_t)b * 2048) * 2048 + h * 64;
  const unsigned short* kbase = qbase + 1024;
  const unsigned short* vbase = vt + (size_t)bh * 64 * 2048;
  const int tp = t & 127;                     // thread index within pair

  bf8 qf[4];
#pragma unroll
  for (int ksl = 0; ksl < 4; ++ksl)
    qf[ksl] = *(const bf8*)(qbase + (size_t)(q0w + q) * 2048 + ksl * 16 + hi * 8);

  f16x oacc[2];
#pragma unroll
  for (int dn = 0; dn < 2; ++dn)
#pragma unroll
    for (int i2 = 0; i2 < 16; ++i2) oacc[dn][i2] = 0.f;
  float l_ = 0.f;

  auto STAGE = [&](int buf, int gi) {
    unsigned short* Kl = &SM[p][buf][0][0];
    unsigned short* Vl = &SM[p][buf][1][0];
#pragma unroll
    for (int ss = 0; ss < 4; ++ss) {
      const int row = ss * 16 + (tp >> 3);
      const int cb = (tp & 7) * 16;           // linear byte col in LDS
      const int sb = cb ^ ((row & 7) << 4);   // pre-swizzled global byte col
      GLOAD_LDS(kbase + (size_t)(gi * 64 + row) * 2048 + (sb >> 1),
                &Kl[row * 64 + (cb >> 1)]);
      GLOAD_LDS(vbase + (size_t)row * 2048 + gi * 64 + (sb >> 1),
                &Vl[row * 64 + (cb >> 1)]);
    }
  };

  // prologue: stage this pair's first tile
  {
    const int gi0 = p ? h0 : 0;
    if (gi0 <= s) STAGE(0, gi0);
  }
  __syncthreads();

  for (int it = 0; it < h0; ++it) {
    const int buf = it & 1;
    const int gi = p ? h0 + it : it;
    const bool act = gi <= s;
    // prefetch next tile into the other buffer (covered by this compute)
    if (it + 1 < h0) {
      const int gin = p ? h0 + it + 1 : it + 1;
      if (gin <= s) STAGE(buf ^ 1, gin);
    }
    if (act) {
      unsigned short* Kl = &SM[p][buf][0][0];
      unsigned short* Vl = &SM[p][buf][1][0];
      const int kb0 = gi * 64;

      // ---- S^T = K @ Q^T for 64 keys (two 32-key groups) ----
      f16x s0, s1;
#pragma unroll
      for (int i2 = 0; i2 < 16; ++i2) { s0[i2] = 0.f; s1[i2] = 0.f; }
      __builtin_amdgcn_s_setprio(1);
#pragma unroll
      for (int ksl = 0; ksl < 4; ++ksl) {
        const int cbq = (ksl * 16 + hi * 8) * 2;
        const int r0 = q, r1 = 32 + q;
        bf8 k0 = *(const bf8*)((const char*)&Kl[r0 * 64] + (cbq ^ ((r0 & 7) << 4)));
        bf8 k1 = *(const bf8*)((const char*)&Kl[r1 * 64] + (cbq ^ ((r1 & 7) << 4)));
        s0 = __builtin_amdgcn_mfma_f32_32x32x16_bf16(k0, qf[ksl], s0, 0, 0, 0);
        s1 = __builtin_amdgcn_mfma_f32_32x32x16_bf16(k1, qf[ksl], s1, 0, 0, 0);
      }
      __builtin_amdgcn_s_setprio(0);

      // ---- causal mask (only at global iter == s); exp2(-1e30) = 0 ----
      float pv[32];
      if (gi == s) {
#pragma unroll
        for (int i2 = 0; i2 < 16; ++i2) {
          const int key = kb0 + (i2 & 3) + 8 * (i2 >> 2) + 4 * hi;
          pv[i2]      = (key <= q0w + q)      ? s0[i2] : -1e30f;
          pv[16 + i2] = (key + 32 <= q0w + q) ? s1[i2] : -1e30f;
        }
      } else {
#pragma unroll
        for (int i2 = 0; i2 < 16; ++i2) { pv[i2] = s0[i2]; pv[16 + i2] = s1[i2]; }
      }

      // ---- fixed-scale softmax: p = exp2(s); l += sum ----
#pragma unroll
      for (int i2 = 0; i2 < 32; ++i2) pv[i2] = __builtin_amdgcn_exp2f(pv[i2]);
      float ts[16];
#pragma unroll
      for (int i2 = 0; i2 < 16; ++i2) ts[i2] = pv[i2] + pv[16 + i2];
#pragma unroll
      for (int st = 8; st >= 1; st >>= 1)
#pragma unroll
        for (int i2 = 0; i2 < 8; ++i2)
          if (i2 < st) ts[i2] += ts[i2 + st];
      l_ += ts[0] + __shfl_xor(ts[0], 32);

      // ---- pack P (v_cvt_pk) + O^T += V^T @ P per 32-key group ----
#pragma unroll
      for (int sg = 0; sg < 2; ++sg) {
        const float* pp = pv + sg * 16;
        unsigned int wds[8];
#pragma unroll
        for (int m = 0; m < 4; ++m) {
          wds[m * 2]     = pk2(pp[4 * m], pp[4 * m + 1]);
          wds[m * 2 + 1] = pk2(pp[4 * m + 2], pp[4 * m + 3]);
        }
#pragma unroll
        for (int kq = 0; kq < 2; ++kq) {
          unsigned int x0 = __shfl_xor((int)(hi ? wds[4 * kq]     : wds[4 * kq + 2]), 32);
          unsigned int x1 = __shfl_xor((int)(hi ? wds[4 * kq + 1] : wds[4 * kq + 3]), 32);
          union { unsigned int u[4]; bf8 v; } pu;
          pu.u[0] = hi ? x0 : wds[4 * kq];
          pu.u[1] = hi ? x1 : wds[4 * kq + 1];
          pu.u[2] = hi ? wds[4 * kq + 2] : x0;
          pu.u[3] = hi ? wds[4 * kq + 3] : x1;
          const bf8 pf = pu.v;
          __builtin_amdgcn_s_setprio(1);
#pragma unroll
          for (int dn = 0; dn < 2; ++dn) {
            const int row = dn * 32 + q;
            const int cb = ((sg * 32 + kq * 16 + hi * 8) * 2) ^ ((row & 7) << 4);
            bf8 vf = *(const bf8*)((const char*)&Vl[row * 64] + cb);
            oacc[dn] = __builtin_amdgcn_mfma_f32_32x32x16_bf16(vf, pf, oacc[dn], 0, 0, 0);
          }
          __builtin_amdgcn_s_setprio(0);
        }
      }
    }
    __syncthreads();   // drains prefetch (already returned: L2-resident KV)
  }

  // ---- merge: out = (O_p0 + O_p1) / (l_p0 + l_p1) ----
  float* mb = (float*)&SM[0][0][0][0];        // 2 regions x 2112 floats
  if (p == 1) {
    float* base = mb + (w & 1) * 2112;
    base[l] = l_;
#pragma unroll
    for (int dn = 0; dn < 2; ++dn)
#pragma unroll
      for (int i2 = 0; i2 < 16; ++i2)
        base[64 + (dn * 16 + i2) * 64 + l] = oacc[dn][i2];
  }
  __syncthreads();
  if (p == 0) {
    float* base = mb + (w & 1) * 2112;
    const float inv = 1.0f / (l_ + base[l]);
    unsigned short* crow = ctx + ((size_t)(b * 2048 + q0w + q)) * 1024 + h * 64;
#pragma unroll
    for (int dn = 0; dn < 2; ++dn)
#pragma unroll
      for (int m = 0; m < 4; ++m) {
        float o0 = oacc[dn][4 * m]     + base[64 + (dn * 16 + 4 * m) * 64 + l];
        float o1 = oacc[dn][4 * m + 1] + base[64 + (dn * 16 + 4 * m + 1) * 64 + l];
        float o2 = oacc[dn][4 * m + 2] + base[64 + (dn * 16 + 4 * m + 2) * 64 + l];
        float o3 = oacc[dn][4 * m + 3] + base[64 + (dn * 16 + 4 * m + 3) * 64 + l];
        const int d0 = dn * 32 + 8 * m + 4 * hi;
        *(unsigned int*)(crow + d0)     = pk2(o0 * inv, o1 * inv);
        *(unsigned int*)(crow + d0 + 2) = pk2(o2 * inv, o3 * inv);
      }
  }
}

// ---------------------------------------------------------------------------
// LayerNorm over rows of 1024 fp32 -> bf16. One block per row (256 thr).
// ---------------------------------------------------------------------------
DEV void ln_row(const float* __restrict__ x, const float* __restrict__ sc,
                const float* __restrict__ sh, unsigned short* __restrict__ out,
                int row, int t)
{
  float4 v = ((const float4*)x)[(size_t)row * 256 + t];
  float s = v.x + v.y + v.z + v.w;
  float q = v.x * v.x + v.y * v.y + v.z * v.z + v.w * v.w;
#pragma unroll
  for (int off = 1; off < 64; off <<= 1) {
    s += __shfl_xor(s, off);
    q += __shfl_xor(q, off);
  }
  __shared__ float red[8];
  const int w = t >> 6, l = t & 63;
  if (l == 0) { red[w] = s; red[4 + w] = q; }
  __syncthreads();
  s = red[0] + red[1] + red[2] + red[3];
  q = red[4] + red[5] + red[6] + red[7];
  const float mean = s * (1.0f / 1024.0f);
  const float var = q * (1.0f / 1024.0f) - mean * mean;
  const float rstd = rsqrtf(var + 1e-5f);
  float4 scv = ((const float4*)sc)[t];
  float4 shv = ((const float4*)sh)[t];
  uint2 p;
  p.x = pk2(scv.x * (v.x - mean) * rstd + shv.x, scv.y * (v.y - mean) * rstd + shv.y);
  p.y = pk2(scv.z * (v.z - mean) * rstd + shv.z, scv.w * (v.w - mean) * rstd + shv.w);
  ((uint2*)out)[(size_t)row * 256 + t] = p;
}

__global__ __launch_bounds__(256) void ln_kernel(
    const float* __restrict__ x, const float* __restrict__ sc,
    const float* __restrict__ sh, unsigned short* __restrict__ out)
{
  ln_row(x, sc, sh, out, blockIdx.x, threadIdx.x);
}

// ---------------------------------------------------------------------------
// Fused launch: blocks [0,4096) do ln1 rows; blocks >= 4096 grid-stride the
// fp32->bf16 weight conversion (wq gets 0.125*log2e folded in).
// ---------------------------------------------------------------------------
__global__ __launch_bounds__(256) void cvt_ln1(
    const float* __restrict__ wq, const float* __restrict__ wk,
    const float* __restrict__ wv, const float* __restrict__ wo,
    const float* __restrict__ w1, const float* __restrict__ w2,
    unsigned short* __restrict__ dst,
    const float* __restrict__ x, const float* __restrict__ ln1s,
    const float* __restrict__ ln1b, unsigned short* __restrict__ lnb)
{
  if (blockIdx.x < 4096) {
    ln_row(x, ln1s, ln1b, lnb, blockIdx.x, threadIdx.x);
    return;
  }
  const int M1 = 1 << 20;
  const int n4 = (12 * M1) / 4;
  const int stride = (gridDim.x - 4096) * 256;
  for (int i4 = (blockIdx.x - 4096) * 256 + threadIdx.x; i4 < n4; i4 += stride) {
    const size_t i = (size_t)i4 * 4;
    const int mi = (int)(i >> 20);
    const float* src;
    size_t off;
    float sc = 1.0f;
    if (mi < 4) {
      src = mi == 0 ? wq : mi == 1 ? wk : mi == 2 ? wv : wo;
      off = i & (size_t)(M1 - 1);
      if (mi == 0) sc = 0.125f * 1.44269504088896f;
    } else if (mi < 8) {
      src = w1; off = i - (size_t)4 * M1;
    } else {
      src = w2; off = i - (size_t)8 * M1;
    }
    float4 v = *(const float4*)(src + off);
    uint2 pq;
    pq.x = pk2(v.x * sc, v.y * sc);
    pq.y = pk2(v.z * sc, v.w * sc);
    ((uint2*)dst)[i4] = pq;
  }
}

// ---------------------------------------------------------------------------
extern "C" void kernel_launch(void* const* d_in, const int* in_sizes, int n_in,
                              void* d_out, int out_size, void* d_ws, size_t ws_size,
                              hipStream_t stream)
{
  const float* x    = (const float*)d_in[0];
  const float* wq   = (const float*)d_in[1];
  const float* wk   = (const float*)d_in[2];
  const float* wv   = (const float*)d_in[3];
  const float* wo   = (const float*)d_in[4];
  const float* bo   = (const float*)d_in[5];
  const float* ln1s = (const float*)d_in[6];
  const float* ln1b = (const float*)d_in[7];
  const float* ln2s = (const float*)d_in[8];
  const float* ln2b = (const float*)d_in[9];
  const float* w1   = (const float*)d_in[10];
  const float* b1   = (const float*)d_in[11];
  const float* w2   = (const float*)d_in[12];
  const float* b2   = (const float*)d_in[13];
  float* out = (float*)d_out;

  const int M = 4096; // B*S

  // workspace (~80 MB)
  unsigned short* ws   = (unsigned short*)d_ws;
  unsigned short* lnb  = ws;                              // [4096,1024]
  unsigned short* qkvw = lnb  + (size_t)4096 * 1024;      // [3072,1024]
  unsigned short* wob  = qkvw + (size_t)3072 * 1024;      // [1024,1024]
  unsigned short* w1b  = wob  + (size_t)1024 * 1024;      // [4096,1024]
  unsigned short* w2b  = w1b  + (size_t)4096 * 1024;      // [1024,4096]
  unsigned short* qkb  = w2b  + (size_t)4096 * 1024;      // [4096,2048] q|k; y1
  unsigned short* vtb  = qkb  + (size_t)4096 * 2048;      // [32,64,2048] V^T
  unsigned short* ctxb = vtb  + (size_t)32 * 64 * 2048;   // [4096,1024]
  float* hf = (float*)(ctxb + (size_t)4096 * 1024);       // [4096,1024] fp32

  // fused: ln1 = LN(x)  +  all weight fp32->bf16 conversions
  cvt_ln1<<<4096 + 2048, 256, 0, stream>>>(
      wq, wk, wv, wo, w1, w2, qkvw, x, ln1s, ln1b, lnb);
  // q|k -> qkb (stride 2048), v -> vtb transposed   [128^2 m97, 768 blocks]
  gemm_bt128<false, false, false, true, true><<<768, 256, 0, stream>>>(
      lnb, qkvw, nullptr, nullptr, qkb, M, 3072, 1024, 2048, vtb, 32);
  // ctx = causal_attention(q,k,v)   [split-KV, double-buffered, fixed-scale]
  attn_kernel<<<1024, 256, 0, stream>>>(qkb, vtb, ctxb);
  // h = x + ctx @ wo^T + bo   (fp32)   [64x128 tiles BK=64]
  gemm_bt64<true, false, true, false><<<512, 256, 0, stream>>>(
      ctxb, wob, bo, x, hf, M, 1024, 1024, 1024);
  // ln2 = LN(h)
  ln_kernel<<<M, 256, 0, stream>>>(hf, ln2s, ln2b, lnb);
  // y1 = relu(ln2 @ w1^T + b1)   [128^2 m97, 1024 blocks]
  gemm_bt128<true, true, false, true, false><<<1024, 256, 0, stream>>>(
      lnb, w1b, b1, nullptr, qkb, M, 4096, 1024, 4096, nullptr, 32);
  // out = h + y1 @ w2^T + b2   [64x128 tiles BK=64]
  gemm_bt64<true, false, true, false><<<512, 256, 0, stream>>>(
      qkb, w2b, b2, hf, out, M, 1024, 4096, 1024);
}

// Round 20
// 230.282 us; speedup vs baseline: 1.0501x; 1.0501x over previous
//
#include <hip/hip_runtime.h>
#include <hip/hip_bf16.h>

#define DEV __device__ __forceinline__

typedef __attribute__((ext_vector_type(8))) short bf8;    // 8 x bf16 (4 VGPRs)
typedef __attribute__((ext_vector_type(4))) float f4;     // 16x16 MFMA acc
typedef __attribute__((ext_vector_type(16))) float f16x;  // 32x32 MFMA acc

#define GLOAD_LDS(gp, lp) \
  __builtin_amdgcn_global_load_lds( \
      (const __attribute__((address_space(1))) void*)(gp), \
      (__attribute__((address_space(3))) void*)(lp), 16, 0, 0)

DEV unsigned short f2bf(float f) {
  union { __hip_bfloat16 h; unsigned short u; } c;
  c.h = __float2bfloat16(f);
  return c.u;
}
DEV unsigned int pk2(float a, float b) {
  union { __hip_bfloat162 h; unsigned int u; } c;
  c.h = __hip_bfloat162(__float2bfloat16(a), __float2bfloat16(b));
  return c.u;
}

// XCD-aware bijective block swizzle + 4-wide N supertiling.
DEV int2 swz_tile(int ob, int nxt, int nyt) {
  const int nb = nxt * nyt;
  const int cpx = nb >> 3;
  const int W = (ob & 7) * cpx + (ob >> 3);
  const int scw = 4 * nyt;
  const int sc = W / scw, rem = W - sc * scw;
  return make_int2(rem >> 2, sc * 4 + (rem & 3));
}

// ---------------------------------------------------------------------------
// 128x128-tile GEMM (QKV / FFN1) — m97-structure: 256 thr = 4 waves (2x2),
// per-wave 64x64 out (4x4 frags), BK=32, 2 LDS slots (32 KB) -> 3-4 blocks/CU.
// 2-phase double-buffer, 1 barrier/K-tile, XCD-swizzled 1D grid.
// WRVT: cols >= 2048 (V of QKV) written transposed to vtout [b*16+h][64][2048].
// ---------------------------------------------------------------------------
template<bool BIAS, bool RELU, bool RESID, bool OUTBF, bool WRVT>
__global__ __launch_bounds__(256) void gemm_bt128(
    const unsigned short* __restrict__ A, const unsigned short* __restrict__ B,
    const float* __restrict__ bias, const float* __restrict__ resid,
    void* __restrict__ Cout, int M, int N, int K, int ldc,
    unsigned short* __restrict__ vtout, int nyt)
{
  __shared__ unsigned short Al[2][128 * 32];
  __shared__ unsigned short Bl[2][128 * 32];
  const int t = threadIdx.x;
  const int w = t >> 6, l = t & 63;
  const int wr = w >> 1, wc = w & 1;
  int2 tt = swz_tile((int)blockIdx.x, N >> 7, nyt);
  const int m0 = tt.x * 128, n0 = tt.y * 128;

  const int srow = w * 16 + (l >> 2);                         // + i*64
  const int scsw = ((l & 3) * 8) ^ (((srow >> 1) & 3) << 3);  // pre-swizzled col
  const unsigned short* Ab = A + (size_t)(m0 + srow) * K + scsw;
  const unsigned short* Bb = B + (size_t)(n0 + srow) * K + scsw;
  const int sdst = w * 512 + l * 8;                           // + i*2048

  auto STAGE = [&](int slot, int k0) {
#pragma unroll
    for (int i = 0; i < 2; ++i) {
      GLOAD_LDS(Ab + (size_t)i * 64 * K + k0, &Al[slot][sdst + i * 2048]);
      GLOAD_LDS(Bb + (size_t)i * 64 * K + k0, &Bl[slot][sdst + i * 2048]);
    }
  };

  const f4 fz = {0.f, 0.f, 0.f, 0.f};
  f4 acc[4][4];
#pragma unroll
  for (int i = 0; i < 4; ++i)
#pragma unroll
    for (int j = 0; j < 4; ++j) acc[i][j] = fz;

  const int NT = K >> 5;
  STAGE(0, 0);
  __syncthreads();

  for (int T = 0; T < NT; ++T) {
    if (T + 1 < NT) STAGE((T + 1) & 1, (T + 1) * 32);
    const int sl = T & 1;
    const int rdcol = ((l >> 4) * 8) ^ ((((l & 15) >> 1) & 3) << 3);
    bf8 af[4], bg[4];
#pragma unroll
    for (int am = 0; am < 4; ++am)
      af[am] = *(const bf8*)&Al[sl][(wr * 64 + am * 16 + (l & 15)) * 32 + rdcol];
#pragma unroll
    for (int bn = 0; bn < 4; ++bn)
      bg[bn] = *(const bf8*)&Bl[sl][(wc * 64 + bn * 16 + (l & 15)) * 32 + rdcol];
    __builtin_amdgcn_s_setprio(1);
#pragma unroll
    for (int am = 0; am < 4; ++am)
#pragma unroll
      for (int bn = 0; bn < 4; ++bn)
        acc[am][bn] = __builtin_amdgcn_mfma_f32_16x16x32_bf16(af[am], bg[bn], acc[am][bn], 0, 0, 0);
    __builtin_amdgcn_s_setprio(0);
    __syncthreads();
  }

#pragma unroll
  for (int bn = 0; bn < 4; ++bn) {
    const int col = n0 + wc * 64 + bn * 16 + (l & 15);
    float bv = 0.f;
    if (BIAS) bv = bias[col];
    const bool isv = WRVT && (col >= 2048);
    const int hh = (col - 2048) >> 6, dd = (col - 2048) & 63;
#pragma unroll
    for (int am = 0; am < 4; ++am) {
#pragma unroll
      for (int r = 0; r < 4; ++r) {
        const int row = m0 + wr * 64 + am * 16 + ((l >> 4) * 4) + r;
        float v = acc[am][bn][r] + bv;
        if (RELU) v = fmaxf(v, 0.f);
        if (RESID) v += resid[(size_t)row * ldc + col];
        if (WRVT && isv) {
          const int bb = row >> 11, ss = row & 2047;
          vtout[((size_t)(bb * 16 + hh) * 64 + dd) * 2048 + ss] = f2bf(v);
        } else if (OUTBF) {
          ((unsigned short*)Cout)[(size_t)row * ldc + col] = f2bf(v);
        } else {
          ((float*)Cout)[(size_t)row * ldc + col] = v;
        }
      }
    }
  }
}

// ---------------------------------------------------------------------------
// 64x128-tile GEMM, BK=64 (WO / FFN2): 2 LDS slots (48 KB), 2-phase
// double-buffer, 1 barrier/K-tile. 256 thr = 4 waves (2x2); per-wave 32x64.
// ---------------------------------------------------------------------------
template<bool BIAS, bool RELU, bool RESID, bool OUTBF>
__global__ __launch_bounds__(256) void gemm_bt64(
    const unsigned short* __restrict__ A, const unsigned short* __restrict__ B,
    const float* __restrict__ bias, const float* __restrict__ resid,
    void* __restrict__ Cout, int M, int N, int K, int ldc)
{
  __shared__ unsigned short Al[2][64 * 64];
  __shared__ unsigned short Bl[2][128 * 64];
  const int t = threadIdx.x;
  const int w = t >> 6, l = t & 63;
  const int wr = w >> 1, wc = w & 1;
  int2 tt = swz_tile((int)blockIdx.x, N >> 7, M >> 6);
  const int m0 = tt.x * 64, n0 = tt.y * 128;

  const int srow = t >> 3;                        // 0..31
  const int scol = 8 * ((t & 7) ^ (srow & 7));    // pre-swizzled elem col
  const unsigned short* Ab = A + (size_t)(m0 + srow) * K + scol;
  const unsigned short* Bb = B + (size_t)(n0 + srow) * K + scol;
  const int sdst = srow * 64 + (t & 7) * 8;

  auto STAGE = [&](int slot, int k0) {
#pragma unroll
    for (int i = 0; i < 2; ++i)
      GLOAD_LDS(Ab + (size_t)(i * 32) * K + k0, &Al[slot][sdst + i * 32 * 64]);
#pragma unroll
    for (int i = 0; i < 4; ++i)
      GLOAD_LDS(Bb + (size_t)(i * 32) * K + k0, &Bl[slot][sdst + i * 32 * 64]);
  };

  const f4 fz = {0.f, 0.f, 0.f, 0.f};
  f4 acc[2][4];
#pragma unroll
  for (int i = 0; i < 2; ++i)
#pragma unroll
    for (int j = 0; j < 4; ++j) acc[i][j] = fz;

  const int NT = K >> 6;
  STAGE(0, 0);
  __syncthreads();

  for (int T = 0; T < NT; ++T) {
    if (T + 1 < NT) STAGE((T + 1) & 1, (T + 1) * 64);
    const int sl = T & 1;
#pragma unroll
    for (int ks = 0; ks < 2; ++ks) {
      const int cb = (ks * 64 + ((l >> 4) * 16)) ^ ((l & 7) << 4);
      bf8 af[2], bg[4];
#pragma unroll
      for (int am = 0; am < 2; ++am)
        af[am] = *(const bf8*)((const char*)&Al[sl][(wr * 32 + am * 16 + (l & 15)) * 64] + cb);
#pragma unroll
      for (int bn = 0; bn < 4; ++bn)
        bg[bn] = *(const bf8*)((const char*)&Bl[sl][(wc * 64 + bn * 16 + (l & 15)) * 64] + cb);
      __builtin_amdgcn_s_setprio(1);
#pragma unroll
      for (int am = 0; am < 2; ++am)
#pragma unroll
        for (int bn = 0; bn < 4; ++bn)
          acc[am][bn] = __builtin_amdgcn_mfma_f32_16x16x32_bf16(af[am], bg[bn], acc[am][bn], 0, 0, 0);
      __builtin_amdgcn_s_setprio(0);
    }
    __syncthreads();
  }

#pragma unroll
  for (int bn = 0; bn < 4; ++bn) {
    const int col = n0 + wc * 64 + bn * 16 + (l & 15);
    float bv = 0.f;
    if (BIAS) bv = bias[col];
#pragma unroll
    for (int am = 0; am < 2; ++am) {
#pragma unroll
      for (int r = 0; r < 4; ++r) {
        const int row = m0 + wr * 32 + am * 16 + ((l >> 4) * 4) + r;
        float v = acc[am][bn][r] + bv;
        if (RELU) v = fmaxf(v, 0.f);
        if (RESID) v += resid[(size_t)row * ldc + col];
        if (OUTBF) ((unsigned short*)Cout)[(size_t)row * ldc + col] = f2bf(v);
        else       ((float*)Cout)[(size_t)row * ldc + col] = v;
      }
    }
  }
}

// ---------------------------------------------------------------------------
// Causal flash attention — split-KV, FIXED-SCALE softmax (R18 version).
// Single-buffered K/V (32 KB LDS -> 4 blocks/CU; cross-block TLP covers the
// load drain — measured better than double-buffering at 2 blocks/CU).
// p = exp2(s) with no running max; out = O/l cancels the scale exactly.
// ---------------------------------------------------------------------------
__global__ __launch_bounds__(256, 4) void attn_kernel(
    const unsigned short* __restrict__ qk, const unsigned short* __restrict__ vt,
    unsigned short* __restrict__ ctx)
{
  __shared__ unsigned short SM[2][2][64 * 64];  // [pair][K=0/V=1][row*64+col]

  const int t = threadIdx.x;
  const int w = t >> 6, l = t & 63;
  const int p = w >> 1;                 // KV half
  const int hi = l >> 5, q = l & 31;
  const int bid = blockIdx.x;
  const int xcd = bid & 7, i = bid >> 3;
  const int g = i >> 5, c = i & 31;
  const int s = (g & 1) ? c : 31 - c;         // anti-correlated CU load
  const int bh = xcd * 4 + g;                 // 4 (b,h) pairs per XCD
  const int b = bh >> 4, h = bh & 15;
  const int tile = 2 * s + (w & 1);
  const int q0w = tile * 32;
  const int h0 = (s + 2) >> 1;

  const unsigned short* qbase = qk + ((size_t)b * 2048) * 2048 + h * 64;
  const unsigned short* kbase = qbase + 1024;
  const unsigned short* vbase = vt + (size_t)bh * 64 * 2048;
  unsigned short* Kl = &SM[p][0][0];
  unsigned short* Vl = &SM[p][1][0];
  const int tp = t & 127;

  bf8 qf[4];
#pragma unroll
  for (int ksl = 0; ksl < 4; ++ksl)
    qf[ksl] = *(const bf8*)(qbase + (size_t)(q0w + q) * 2048 + ksl * 16 + hi * 8);

  f16x oacc[2];
#pragma unroll
  for (int dn = 0; dn < 2; ++dn)
#pragma unroll
    for (int i2 = 0; i2 < 16; ++i2) oacc[dn][i2] = 0.f;
  float l_ = 0.f;

  for (int it = 0; it < h0; ++it) {
    const int gi = p ? h0 + it : it;
    const bool act = gi <= s;
    __syncthreads();
    if (act) {
#pragma unroll
      for (int ss = 0; ss < 4; ++ss) {
        const int row = ss * 16 + (tp >> 3);
        const int cb = (tp & 7) * 16;
        const int sb = cb ^ ((row & 7) << 4);
        GLOAD_LDS(kbase + (size_t)(gi * 64 + row) * 2048 + (sb >> 1),
                  &Kl[row * 64 + (cb >> 1)]);
        GLOAD_LDS(vbase + (size_t)row * 2048 + gi * 64 + (sb >> 1),
                  &Vl[row * 64 + (cb >> 1)]);
      }
    }
    __syncthreads();
    if (act) {
      const int kb0 = gi * 64;

      // ---- S^T = K @ Q^T for 64 keys (two 32-key groups) ----
      f16x s0, s1;
#pragma unroll
      for (int i2 = 0; i2 < 16; ++i2) { s0[i2] = 0.f; s1[i2] = 0.f; }
      __builtin_amdgcn_s_setprio(1);
#pragma unroll
      for (int ksl = 0; ksl < 4; ++ksl) {
        const int cbq = (ksl * 16 + hi * 8) * 2;
        const int r0 = q, r1 = 32 + q;
        bf8 k0 = *(const bf8*)((const char*)&Kl[r0 * 64] + (cbq ^ ((r0 & 7) << 4)));
        bf8 k1 = *(const bf8*)((const char*)&Kl[r1 * 64] + (cbq ^ ((r1 & 7) << 4)));
        s0 = __builtin_amdgcn_mfma_f32_32x32x16_bf16(k0, qf[ksl], s0, 0, 0, 0);
        s1 = __builtin_amdgcn_mfma_f32_32x32x16_bf16(k1, qf[ksl], s1, 0, 0, 0);
      }
      __builtin_amdgcn_s_setprio(0);

      // ---- causal mask (only at global iter == s); exp2(-1e30) = 0 ----
      float pv[32];
      if (gi == s) {
#pragma unroll
        for (int i2 = 0; i2 < 16; ++i2) {
          const int key = kb0 + (i2 & 3) + 8 * (i2 >> 2) + 4 * hi;
          pv[i2]      = (key <= q0w + q)      ? s0[i2] : -1e30f;
          pv[16 + i2] = (key + 32 <= q0w + q) ? s1[i2] : -1e30f;
        }
      } else {
#pragma unroll
        for (int i2 = 0; i2 < 16; ++i2) { pv[i2] = s0[i2]; pv[16 + i2] = s1[i2]; }
      }

      // ---- fixed-scale softmax: p = exp2(s); l += sum (no max tracking) ----
#pragma unroll
      for (int i2 = 0; i2 < 32; ++i2) pv[i2] = __builtin_amdgcn_exp2f(pv[i2]);
      float ts[16];
#pragma unroll
      for (int i2 = 0; i2 < 16; ++i2) ts[i2] = pv[i2] + pv[16 + i2];
#pragma unroll
      for (int st = 8; st >= 1; st >>= 1)
#pragma unroll
        for (int i2 = 0; i2 < 8; ++i2)
          if (i2 < st) ts[i2] += ts[i2 + st];
      l_ += ts[0] + __shfl_xor(ts[0], 32);

      // ---- pack P (v_cvt_pk) + O^T += V^T @ P per 32-key group ----
#pragma unroll
      for (int sg = 0; sg < 2; ++sg) {
        const float* pp = pv + sg * 16;
        unsigned int wds[8];
#pragma unroll
        for (int m = 0; m < 4; ++m) {
          wds[m * 2]     = pk2(pp[4 * m], pp[4 * m + 1]);
          wds[m * 2 + 1] = pk2(pp[4 * m + 2], pp[4 * m + 3]);
        }
#pragma unroll
        for (int kq = 0; kq < 2; ++kq) {
          unsigned int x0 = __shfl_xor((int)(hi ? wds[4 * kq]     : wds[4 * kq + 2]), 32);
          unsigned int x1 = __shfl_xor((int)(hi ? wds[4 * kq + 1] : wds[4 * kq + 3]), 32);
          union { unsigned int u[4]; bf8 v; } pu;
          pu.u[0] = hi ? x0 : wds[4 * kq];
          pu.u[1] = hi ? x1 : wds[4 * kq + 1];
          pu.u[2] = hi ? wds[4 * kq + 2] : x0;
          pu.u[3] = hi ? wds[4 * kq + 3] : x1;
          const bf8 pf = pu.v;
          __builtin_amdgcn_s_setprio(1);
#pragma unroll
          for (int dn = 0; dn < 2; ++dn) {
            const int row = dn * 32 + q;
            const int cb = ((sg * 32 + kq * 16 + hi * 8) * 2) ^ ((row & 7) << 4);
            bf8 vf = *(const bf8*)((const char*)&Vl[row * 64] + cb);
            oacc[dn] = __builtin_amdgcn_mfma_f32_32x32x16_bf16(vf, pf, oacc[dn], 0, 0, 0);
          }
          __builtin_amdgcn_s_setprio(0);
        }
      }
    }
  }

  // ---- merge: out = (O_p0 + O_p1) / (l_p0 + l_p1) ----
  __syncthreads();
  float* mb = (float*)&SM[0][0][0];           // 2 regions x 2112 floats
  if (p == 1) {
    float* base = mb + (w & 1) * 2112;
    base[l] = l_;
#pragma unroll
    for (int dn = 0; dn < 2; ++dn)
#pragma unroll
      for (int i2 = 0; i2 < 16; ++i2)
        base[64 + (dn * 16 + i2) * 64 + l] = oacc[dn][i2];
  }
  __syncthreads();
  if (p == 0) {
    float* base = mb + (w & 1) * 2112;
    const float inv = 1.0f / (l_ + base[l]);
    unsigned short* crow = ctx + ((size_t)(b * 2048 + q0w + q)) * 1024 + h * 64;
#pragma unroll
    for (int dn = 0; dn < 2; ++dn)
#pragma unroll
      for (int m = 0; m < 4; ++m) {
        float o0 = oacc[dn][4 * m]     + base[64 + (dn * 16 + 4 * m) * 64 + l];
        float o1 = oacc[dn][4 * m + 1] + base[64 + (dn * 16 + 4 * m + 1) * 64 + l];
        float o2 = oacc[dn][4 * m + 2] + base[64 + (dn * 16 + 4 * m + 2) * 64 + l];
        float o3 = oacc[dn][4 * m + 3] + base[64 + (dn * 16 + 4 * m + 3) * 64 + l];
        const int d0 = dn * 32 + 8 * m + 4 * hi;
        *(unsigned int*)(crow + d0)     = pk2(o0 * inv, o1 * inv);
        *(unsigned int*)(crow + d0 + 2) = pk2(o2 * inv, o3 * inv);
      }
  }
}

// ---------------------------------------------------------------------------
// LayerNorm over rows of 1024 fp32 -> bf16. One block per row (256 thr).
// ---------------------------------------------------------------------------
DEV void ln_row(const float* __restrict__ x, const float* __restrict__ sc,
                const float* __restrict__ sh, unsigned short* __restrict__ out,
                int row, int t)
{
  float4 v = ((const float4*)x)[(size_t)row * 256 + t];
  float s = v.x + v.y + v.z + v.w;
  float q = v.x * v.x + v.y * v.y + v.z * v.z + v.w * v.w;
#pragma unroll
  for (int off = 1; off < 64; off <<= 1) {
    s += __shfl_xor(s, off);
    q += __shfl_xor(q, off);
  }
  __shared__ float red[8];
  const int w = t >> 6, l = t & 63;
  if (l == 0) { red[w] = s; red[4 + w] = q; }
  __syncthreads();
  s = red[0] + red[1] + red[2] + red[3];
  q = red[4] + red[5] + red[6] + red[7];
  const float mean = s * (1.0f / 1024.0f);
  const float var = q * (1.0f / 1024.0f) - mean * mean;
  const float rstd = rsqrtf(var + 1e-5f);
  float4 scv = ((const float4*)sc)[t];
  float4 shv = ((const float4*)sh)[t];
  uint2 p;
  p.x = pk2(scv.x * (v.x - mean) * rstd + shv.x, scv.y * (v.y - mean) * rstd + shv.y);
  p.y = pk2(scv.z * (v.z - mean) * rstd + shv.z, scv.w * (v.w - mean) * rstd + shv.w);
  ((uint2*)out)[(size_t)row * 256 + t] = p;
}

__global__ __launch_bounds__(256) void ln_kernel(
    const float* __restrict__ x, const float* __restrict__ sc,
    const float* __restrict__ sh, unsigned short* __restrict__ out)
{
  ln_row(x, sc, sh, out, blockIdx.x, threadIdx.x);
}

// ---------------------------------------------------------------------------
// Fused launch: blocks [0,4096) do ln1 rows; blocks >= 4096 grid-stride the
// fp32->bf16 weight conversion (wq gets 0.125*log2e folded in).
// ---------------------------------------------------------------------------
__global__ __launch_bounds__(256) void cvt_ln1(
    const float* __restrict__ wq, const float* __restrict__ wk,
    const float* __restrict__ wv, const float* __restrict__ wo,
    const float* __restrict__ w1, const float* __restrict__ w2,
    unsigned short* __restrict__ dst,
    const float* __restrict__ x, const float* __restrict__ ln1s,
    const float* __restrict__ ln1b, unsigned short* __restrict__ lnb)
{
  if (blockIdx.x < 4096) {
    ln_row(x, ln1s, ln1b, lnb, blockIdx.x, threadIdx.x);
    return;
  }
  const int M1 = 1 << 20;
  const int n4 = (12 * M1) / 4;
  const int stride = (gridDim.x - 4096) * 256;
  for (int i4 = (blockIdx.x - 4096) * 256 + threadIdx.x; i4 < n4; i4 += stride) {
    const size_t i = (size_t)i4 * 4;
    const int mi = (int)(i >> 20);
    const float* src;
    size_t off;
    float sc = 1.0f;
    if (mi < 4) {
      src = mi == 0 ? wq : mi == 1 ? wk : mi == 2 ? wv : wo;
      off = i & (size_t)(M1 - 1);
      if (mi == 0) sc = 0.125f * 1.44269504088896f;
    } else if (mi < 8) {
      src = w1; off = i - (size_t)4 * M1;
    } else {
      src = w2; off = i - (size_t)8 * M1;
    }
    float4 v = *(const float4*)(src + off);
    uint2 pq;
    pq.x = pk2(v.x * sc, v.y * sc);
    pq.y = pk2(v.z * sc, v.w * sc);
    ((uint2*)dst)[i4] = pq;
  }
}

// ---------------------------------------------------------------------------
extern "C" void kernel_launch(void* const* d_in, const int* in_sizes, int n_in,
                              void* d_out, int out_size, void* d_ws, size_t ws_size,
                              hipStream_t stream)
{
  const float* x    = (const float*)d_in[0];
  const float* wq   = (const float*)d_in[1];
  const float* wk   = (const float*)d_in[2];
  const float* wv   = (const float*)d_in[3];
  const float* wo   = (const float*)d_in[4];
  const float* bo   = (const float*)d_in[5];
  const float* ln1s = (const float*)d_in[6];
  const float* ln1b = (const float*)d_in[7];
  const float* ln2s = (const float*)d_in[8];
  const float* ln2b = (const float*)d_in[9];
  const float* w1   = (const float*)d_in[10];
  const float* b1   = (const float*)d_in[11];
  const float* w2   = (const float*)d_in[12];
  const float* b2   = (const float*)d_in[13];
  float* out = (float*)d_out;

  const int M = 4096; // B*S

  // workspace (~80 MB)
  unsigned short* ws   = (unsigned short*)d_ws;
  unsigned short* lnb  = ws;                              // [4096,1024]
  unsigned short* qkvw = lnb  + (size_t)4096 * 1024;      // [3072,1024]
  unsigned short* wob  = qkvw + (size_t)3072 * 1024;      // [1024,1024]
  unsigned short* w1b  = wob  + (size_t)1024 * 1024;      // [4096,1024]
  unsigned short* w2b  = w1b  + (size_t)4096 * 1024;      // [1024,4096]
  unsigned short* qkb  = w2b  + (size_t)4096 * 1024;      // [4096,2048] q|k; y1
  unsigned short* vtb  = qkb  + (size_t)4096 * 2048;      // [32,64,2048] V^T
  unsigned short* ctxb = vtb  + (size_t)32 * 64 * 2048;   // [4096,1024]
  float* hf = (float*)(ctxb + (size_t)4096 * 1024);       // [4096,1024] fp32

  // fused: ln1 = LN(x)  +  all weight fp32->bf16 conversions
  cvt_ln1<<<4096 + 2048, 256, 0, stream>>>(
      wq, wk, wv, wo, w1, w2, qkvw, x, ln1s, ln1b, lnb);
  // q|k -> qkb (stride 2048), v -> vtb transposed   [128^2 m97, 768 blocks]
  gemm_bt128<false, false, false, true, true><<<768, 256, 0, stream>>>(
      lnb, qkvw, nullptr, nullptr, qkb, M, 3072, 1024, 2048, vtb, 32);
  // ctx = causal_attention(q,k,v)   [split-KV, fixed-scale softmax]
  attn_kernel<<<1024, 256, 0, stream>>>(qkb, vtb, ctxb);
  // h = x + ctx @ wo^T + bo   (fp32)   [64x128 tiles BK=64]
  gemm_bt64<true, false, true, false><<<512, 256, 0, stream>>>(
      ctxb, wob, bo, x, hf, M, 1024, 1024, 1024);
  // ln2 = LN(h)
  ln_kernel<<<M, 256, 0, stream>>>(hf, ln2s, ln2b, lnb);
  // y1 = relu(ln2 @ w1^T + b1)   [128^2 m97, 1024 blocks]
  gemm_bt128<true, true, false, true, false><<<1024, 256, 0, stream>>>(
      lnb, w1b, b1, nullptr, qkb, M, 4096, 1024, 4096, nullptr, 32);
  // out = h + y1 @ w2^T + b2   [64x128 tiles BK=64]
  gemm_bt64<true, false, true, false><<<512, 256, 0, stream>>>(
      qkb, w2b, b2, hf, out, M, 1024, 4096, 1024);
}

// Round 21
// 229.653 us; speedup vs baseline: 1.0530x; 1.0027x over previous
//
#include <hip/hip_runtime.h>
#include <hip/hip_bf16.h>

#define DEV __device__ __forceinline__

typedef __attribute__((ext_vector_type(8))) short bf8;    // 8 x bf16 (4 VGPRs)
typedef __attribute__((ext_vector_type(4))) float f4;     // 16x16 MFMA acc
typedef __attribute__((ext_vector_type(16))) float f16x;  // 32x32 MFMA acc

#define GLOAD_LDS(gp, lp) \
  __builtin_amdgcn_global_load_lds( \
      (const __attribute__((address_space(1))) void*)(gp), \
      (__attribute__((address_space(3))) void*)(lp), 16, 0, 0)

DEV unsigned short f2bf(float f) {
  union { __hip_bfloat16 h; unsigned short u; } c;
  c.h = __float2bfloat16(f);
  return c.u;
}
DEV unsigned int pk2(float a, float b) {
  union { __hip_bfloat162 h; unsigned int u; } c;
  c.h = __hip_bfloat162(__float2bfloat16(a), __float2bfloat16(b));
  return c.u;
}

// XCD-aware bijective block swizzle + 4-wide N supertiling.
DEV int2 swz_tile(int ob, int nxt, int nyt) {
  const int nb = nxt * nyt;
  const int cpx = nb >> 3;
  const int W = (ob & 7) * cpx + (ob >> 3);
  const int scw = 4 * nyt;
  const int sc = W / scw, rem = W - sc * scw;
  return make_int2(rem >> 2, sc * 4 + (rem & 3));
}

// ---------------------------------------------------------------------------
// 128x128-tile GEMM (QKV / FFN1) — m97-structure: 256 thr = 4 waves (2x2),
// per-wave 64x64 out (4x4 frags), BK=32, 2 LDS slots (32 KB) -> 3-4 blocks/CU.
// 2-phase double-buffer, 1 barrier/K-tile, XCD-swizzled 1D grid.
// WRVT: cols >= 2048 (V of QKV) written transposed to vtout [b*16+h][64][2048].
// ---------------------------------------------------------------------------
template<bool BIAS, bool RELU, bool RESID, bool OUTBF, bool WRVT>
__global__ __launch_bounds__(256) void gemm_bt128(
    const unsigned short* __restrict__ A, const unsigned short* __restrict__ B,
    const float* __restrict__ bias, const float* __restrict__ resid,
    void* __restrict__ Cout, int M, int N, int K, int ldc,
    unsigned short* __restrict__ vtout, int nyt)
{
  __shared__ unsigned short Al[2][128 * 32];
  __shared__ unsigned short Bl[2][128 * 32];
  const int t = threadIdx.x;
  const int w = t >> 6, l = t & 63;
  const int wr = w >> 1, wc = w & 1;
  int2 tt = swz_tile((int)blockIdx.x, N >> 7, nyt);
  const int m0 = tt.x * 128, n0 = tt.y * 128;

  const int srow = w * 16 + (l >> 2);                         // + i*64
  const int scsw = ((l & 3) * 8) ^ (((srow >> 1) & 3) << 3);  // pre-swizzled col
  const unsigned short* Ab = A + (size_t)(m0 + srow) * K + scsw;
  const unsigned short* Bb = B + (size_t)(n0 + srow) * K + scsw;
  const int sdst = w * 512 + l * 8;                           // + i*2048

  auto STAGE = [&](int slot, int k0) {
#pragma unroll
    for (int i = 0; i < 2; ++i) {
      GLOAD_LDS(Ab + (size_t)i * 64 * K + k0, &Al[slot][sdst + i * 2048]);
      GLOAD_LDS(Bb + (size_t)i * 64 * K + k0, &Bl[slot][sdst + i * 2048]);
    }
  };

  const f4 fz = {0.f, 0.f, 0.f, 0.f};
  f4 acc[4][4];
#pragma unroll
  for (int i = 0; i < 4; ++i)
#pragma unroll
    for (int j = 0; j < 4; ++j) acc[i][j] = fz;

  const int NT = K >> 5;
  STAGE(0, 0);
  __syncthreads();

  for (int T = 0; T < NT; ++T) {
    if (T + 1 < NT) STAGE((T + 1) & 1, (T + 1) * 32);
    const int sl = T & 1;
    const int rdcol = ((l >> 4) * 8) ^ ((((l & 15) >> 1) & 3) << 3);
    bf8 af[4], bg[4];
#pragma unroll
    for (int am = 0; am < 4; ++am)
      af[am] = *(const bf8*)&Al[sl][(wr * 64 + am * 16 + (l & 15)) * 32 + rdcol];
#pragma unroll
    for (int bn = 0; bn < 4; ++bn)
      bg[bn] = *(const bf8*)&Bl[sl][(wc * 64 + bn * 16 + (l & 15)) * 32 + rdcol];
    __builtin_amdgcn_s_setprio(1);
#pragma unroll
    for (int am = 0; am < 4; ++am)
#pragma unroll
      for (int bn = 0; bn < 4; ++bn)
        acc[am][bn] = __builtin_amdgcn_mfma_f32_16x16x32_bf16(af[am], bg[bn], acc[am][bn], 0, 0, 0);
    __builtin_amdgcn_s_setprio(0);
    __syncthreads();
  }

#pragma unroll
  for (int bn = 0; bn < 4; ++bn) {
    const int col = n0 + wc * 64 + bn * 16 + (l & 15);
    float bv = 0.f;
    if (BIAS) bv = bias[col];
    const bool isv = WRVT && (col >= 2048);
    const int hh = (col - 2048) >> 6, dd = (col - 2048) & 63;
#pragma unroll
    for (int am = 0; am < 4; ++am) {
#pragma unroll
      for (int r = 0; r < 4; ++r) {
        const int row = m0 + wr * 64 + am * 16 + ((l >> 4) * 4) + r;
        float v = acc[am][bn][r] + bv;
        if (RELU) v = fmaxf(v, 0.f);
        if (RESID) v += resid[(size_t)row * ldc + col];
        if (WRVT && isv) {
          const int bb = row >> 11, ss = row & 2047;
          vtout[((size_t)(bb * 16 + hh) * 64 + dd) * 2048 + ss] = f2bf(v);
        } else if (OUTBF) {
          ((unsigned short*)Cout)[(size_t)row * ldc + col] = f2bf(v);
        } else {
          ((float*)Cout)[(size_t)row * ldc + col] = v;
        }
      }
    }
  }
}

// ---------------------------------------------------------------------------
// 64x128-tile GEMM, BK=64 (WO / FFN2): 2 LDS slots (48 KB), 2-phase
// double-buffer, 1 barrier/K-tile. 256 thr = 4 waves (2x2); per-wave 32x64.
// ---------------------------------------------------------------------------
template<bool BIAS, bool RELU, bool RESID, bool OUTBF>
__global__ __launch_bounds__(256) void gemm_bt64(
    const unsigned short* __restrict__ A, const unsigned short* __restrict__ B,
    const float* __restrict__ bias, const float* __restrict__ resid,
    void* __restrict__ Cout, int M, int N, int K, int ldc)
{
  __shared__ unsigned short Al[2][64 * 64];
  __shared__ unsigned short Bl[2][128 * 64];
  const int t = threadIdx.x;
  const int w = t >> 6, l = t & 63;
  const int wr = w >> 1, wc = w & 1;
  int2 tt = swz_tile((int)blockIdx.x, N >> 7, M >> 6);
  const int m0 = tt.x * 64, n0 = tt.y * 128;

  const int srow = t >> 3;                        // 0..31
  const int scol = 8 * ((t & 7) ^ (srow & 7));    // pre-swizzled elem col
  const unsigned short* Ab = A + (size_t)(m0 + srow) * K + scol;
  const unsigned short* Bb = B + (size_t)(n0 + srow) * K + scol;
  const int sdst = srow * 64 + (t & 7) * 8;

  auto STAGE = [&](int slot, int k0) {
#pragma unroll
    for (int i = 0; i < 2; ++i)
      GLOAD_LDS(Ab + (size_t)(i * 32) * K + k0, &Al[slot][sdst + i * 32 * 64]);
#pragma unroll
    for (int i = 0; i < 4; ++i)
      GLOAD_LDS(Bb + (size_t)(i * 32) * K + k0, &Bl[slot][sdst + i * 32 * 64]);
  };

  const f4 fz = {0.f, 0.f, 0.f, 0.f};
  f4 acc[2][4];
#pragma unroll
  for (int i = 0; i < 2; ++i)
#pragma unroll
    for (int j = 0; j < 4; ++j) acc[i][j] = fz;

  const int NT = K >> 6;
  STAGE(0, 0);
  __syncthreads();

  for (int T = 0; T < NT; ++T) {
    if (T + 1 < NT) STAGE((T + 1) & 1, (T + 1) * 64);
    const int sl = T & 1;
#pragma unroll
    for (int ks = 0; ks < 2; ++ks) {
      const int cb = (ks * 64 + ((l >> 4) * 16)) ^ ((l & 7) << 4);
      bf8 af[2], bg[4];
#pragma unroll
      for (int am = 0; am < 2; ++am)
        af[am] = *(const bf8*)((const char*)&Al[sl][(wr * 32 + am * 16 + (l & 15)) * 64] + cb);
#pragma unroll
      for (int bn = 0; bn < 4; ++bn)
        bg[bn] = *(const bf8*)((const char*)&Bl[sl][(wc * 64 + bn * 16 + (l & 15)) * 64] + cb);
      __builtin_amdgcn_s_setprio(1);
#pragma unroll
      for (int am = 0; am < 2; ++am)
#pragma unroll
        for (int bn = 0; bn < 4; ++bn)
          acc[am][bn] = __builtin_amdgcn_mfma_f32_16x16x32_bf16(af[am], bg[bn], acc[am][bn], 0, 0, 0);
      __builtin_amdgcn_s_setprio(0);
    }
    __syncthreads();
  }

#pragma unroll
  for (int bn = 0; bn < 4; ++bn) {
    const int col = n0 + wc * 64 + bn * 16 + (l & 15);
    float bv = 0.f;
    if (BIAS) bv = bias[col];
#pragma unroll
    for (int am = 0; am < 2; ++am) {
#pragma unroll
      for (int r = 0; r < 4; ++r) {
        const int row = m0 + wr * 32 + am * 16 + ((l >> 4) * 4) + r;
        float v = acc[am][bn][r] + bv;
        if (RELU) v = fmaxf(v, 0.f);
        if (RESID) v += resid[(size_t)row * ldc + col];
        if (OUTBF) ((unsigned short*)Cout)[(size_t)row * ldc + col] = f2bf(v);
        else       ((float*)Cout)[(size_t)row * ldc + col] = v;
      }
    }
  }
}

// ---------------------------------------------------------------------------
// Causal flash attention — split-KV, FIXED-SCALE softmax.
// Single-buffered K/V (32 KB LDS -> 4 blocks/CU; cross-block TLP covers the
// load drain — measured better than double-buffering at 2 blocks/CU).
// p = exp2(s) with no running max; out = O/l cancels the scale exactly.
// ---------------------------------------------------------------------------
__global__ __launch_bounds__(256, 4) void attn_kernel(
    const unsigned short* __restrict__ qk, const unsigned short* __restrict__ vt,
    unsigned short* __restrict__ ctx)
{
  __shared__ unsigned short SM[2][2][64 * 64];  // [pair][K=0/V=1][row*64+col]

  const int t = threadIdx.x;
  const int w = t >> 6, l = t & 63;
  const int p = w >> 1;                 // KV half
  const int hi = l >> 5, q = l & 31;
  const int bid = blockIdx.x;
  const int xcd = bid & 7, i = bid >> 3;
  const int g = i >> 5, c = i & 31;
  const int s = (g & 1) ? c : 31 - c;         // anti-correlated CU load
  const int bh = xcd * 4 + g;                 // 4 (b,h) pairs per XCD
  const int b = bh >> 4, h = bh & 15;
  const int tile = 2 * s + (w & 1);
  const int q0w = tile * 32;
  const int h0 = (s + 2) >> 1;

  const unsigned short* qbase = qk + ((size_t)b * 2048) * 2048 + h * 64;
  const unsigned short* kbase = qbase + 1024;
  const unsigned short* vbase = vt + (size_t)bh * 64 * 2048;
  unsigned short* Kl = &SM[p][0][0];
  unsigned short* Vl = &SM[p][1][0];
  const int tp = t & 127;

  bf8 qf[4];
#pragma unroll
  for (int ksl = 0; ksl < 4; ++ksl)
    qf[ksl] = *(const bf8*)(qbase + (size_t)(q0w + q) * 2048 + ksl * 16 + hi * 8);

  f16x oacc[2];
#pragma unroll
  for (int dn = 0; dn < 2; ++dn)
#pragma unroll
    for (int i2 = 0; i2 < 16; ++i2) oacc[dn][i2] = 0.f;
  float l_ = 0.f;

  for (int it = 0; it < h0; ++it) {
    const int gi = p ? h0 + it : it;
    const bool act = gi <= s;
    __syncthreads();
    if (act) {
#pragma unroll
      for (int ss = 0; ss < 4; ++ss) {
        const int row = ss * 16 + (tp >> 3);
        const int cb = (tp & 7) * 16;
        const int sb = cb ^ ((row & 7) << 4);
        GLOAD_LDS(kbase + (size_t)(gi * 64 + row) * 2048 + (sb >> 1),
                  &Kl[row * 64 + (cb >> 1)]);
        GLOAD_LDS(vbase + (size_t)row * 2048 + gi * 64 + (sb >> 1),
                  &Vl[row * 64 + (cb >> 1)]);
      }
    }
    __syncthreads();
    if (act) {
      const int kb0 = gi * 64;

      // ---- S^T = K @ Q^T for 64 keys (two 32-key groups) ----
      f16x s0, s1;
#pragma unroll
      for (int i2 = 0; i2 < 16; ++i2) { s0[i2] = 0.f; s1[i2] = 0.f; }
      __builtin_amdgcn_s_setprio(1);
#pragma unroll
      for (int ksl = 0; ksl < 4; ++ksl) {
        const int cbq = (ksl * 16 + hi * 8) * 2;
        const int r0 = q, r1 = 32 + q;
        bf8 k0 = *(const bf8*)((const char*)&Kl[r0 * 64] + (cbq ^ ((r0 & 7) << 4)));
        bf8 k1 = *(const bf8*)((const char*)&Kl[r1 * 64] + (cbq ^ ((r1 & 7) << 4)));
        s0 = __builtin_amdgcn_mfma_f32_32x32x16_bf16(k0, qf[ksl], s0, 0, 0, 0);
        s1 = __builtin_amdgcn_mfma_f32_32x32x16_bf16(k1, qf[ksl], s1, 0, 0, 0);
      }
      __builtin_amdgcn_s_setprio(0);

      // ---- causal mask (only at global iter == s); exp2(-1e30) = 0 ----
      float pv[32];
      if (gi == s) {
#pragma unroll
        for (int i2 = 0; i2 < 16; ++i2) {
          const int key = kb0 + (i2 & 3) + 8 * (i2 >> 2) + 4 * hi;
          pv[i2]      = (key <= q0w + q)      ? s0[i2] : -1e30f;
          pv[16 + i2] = (key + 32 <= q0w + q) ? s1[i2] : -1e30f;
        }
      } else {
#pragma unroll
        for (int i2 = 0; i2 < 16; ++i2) { pv[i2] = s0[i2]; pv[16 + i2] = s1[i2]; }
      }

      // ---- fixed-scale softmax: p = exp2(s); l += sum (no max tracking) ----
#pragma unroll
      for (int i2 = 0; i2 < 32; ++i2) pv[i2] = __builtin_amdgcn_exp2f(pv[i2]);
      float ts[16];
#pragma unroll
      for (int i2 = 0; i2 < 16; ++i2) ts[i2] = pv[i2] + pv[16 + i2];
#pragma unroll
      for (int st = 8; st >= 1; st >>= 1)
#pragma unroll
        for (int i2 = 0; i2 < 8; ++i2)
          if (i2 < st) ts[i2] += ts[i2 + st];
      l_ += ts[0] + __shfl_xor(ts[0], 32);

      // ---- pack P (v_cvt_pk) + O^T += V^T @ P per 32-key group ----
#pragma unroll
      for (int sg = 0; sg < 2; ++sg) {
        const float* pp = pv + sg * 16;
        unsigned int wds[8];
#pragma unroll
        for (int m = 0; m < 4; ++m) {
          wds[m * 2]     = pk2(pp[4 * m], pp[4 * m + 1]);
          wds[m * 2 + 1] = pk2(pp[4 * m + 2], pp[4 * m + 3]);
        }
#pragma unroll
        for (int kq = 0; kq < 2; ++kq) {
          unsigned int x0 = __shfl_xor((int)(hi ? wds[4 * kq]     : wds[4 * kq + 2]), 32);
          unsigned int x1 = __shfl_xor((int)(hi ? wds[4 * kq + 1] : wds[4 * kq + 3]), 32);
          union { unsigned int u[4]; bf8 v; } pu;
          pu.u[0] = hi ? x0 : wds[4 * kq];
          pu.u[1] = hi ? x1 : wds[4 * kq + 1];
          pu.u[2] = hi ? wds[4 * kq + 2] : x0;
          pu.u[3] = hi ? wds[4 * kq + 3] : x1;
          const bf8 pf = pu.v;
          __builtin_amdgcn_s_setprio(1);
#pragma unroll
          for (int dn = 0; dn < 2; ++dn) {
            const int row = dn * 32 + q;
            const int cb = ((sg * 32 + kq * 16 + hi * 8) * 2) ^ ((row & 7) << 4);
            bf8 vf = *(const bf8*)((const char*)&Vl[row * 64] + cb);
            oacc[dn] = __builtin_amdgcn_mfma_f32_32x32x16_bf16(vf, pf, oacc[dn], 0, 0, 0);
          }
          __builtin_amdgcn_s_setprio(0);
        }
      }
    }
  }

  // ---- merge: out = (O_p0 + O_p1) / (l_p0 + l_p1) ----
  __syncthreads();
  float* mb = (float*)&SM[0][0][0];           // 2 regions x 2112 floats
  if (p == 1) {
    float* base = mb + (w & 1) * 2112;
    base[l] = l_;
#pragma unroll
    for (int dn = 0; dn < 2; ++dn)
#pragma unroll
      for (int i2 = 0; i2 < 16; ++i2)
        base[64 + (dn * 16 + i2) * 64 + l] = oacc[dn][i2];
  }
  __syncthreads();
  if (p == 0) {
    float* base = mb + (w & 1) * 2112;
    const float inv = 1.0f / (l_ + base[l]);
    unsigned short* crow = ctx + ((size_t)(b * 2048 + q0w + q)) * 1024 + h * 64;
#pragma unroll
    for (int dn = 0; dn < 2; ++dn)
#pragma unroll
      for (int m = 0; m < 4; ++m) {
        float o0 = oacc[dn][4 * m]     + base[64 + (dn * 16 + 4 * m) * 64 + l];
        float o1 = oacc[dn][4 * m + 1] + base[64 + (dn * 16 + 4 * m + 1) * 64 + l];
        float o2 = oacc[dn][4 * m + 2] + base[64 + (dn * 16 + 4 * m + 2) * 64 + l];
        float o3 = oacc[dn][4 * m + 3] + base[64 + (dn * 16 + 4 * m + 3) * 64 + l];
        const int d0 = dn * 32 + 8 * m + 4 * hi;
        *(unsigned int*)(crow + d0)     = pk2(o0 * inv, o1 * inv);
        *(unsigned int*)(crow + d0 + 2) = pk2(o2 * inv, o3 * inv);
      }
  }
}

// ---------------------------------------------------------------------------
// LayerNorm over rows of 1024 fp32 -> bf16. One block per row (256 thr).
// ---------------------------------------------------------------------------
DEV void ln_row(const float* __restrict__ x, const float* __restrict__ sc,
                const float* __restrict__ sh, unsigned short* __restrict__ out,
                int row, int t)
{
  float4 v = ((const float4*)x)[(size_t)row * 256 + t];
  float s = v.x + v.y + v.z + v.w;
  float q = v.x * v.x + v.y * v.y + v.z * v.z + v.w * v.w;
#pragma unroll
  for (int off = 1; off < 64; off <<= 1) {
    s += __shfl_xor(s, off);
    q += __shfl_xor(q, off);
  }
  __shared__ float red[8];
  const int w = t >> 6, l = t & 63;
  if (l == 0) { red[w] = s; red[4 + w] = q; }
  __syncthreads();
  s = red[0] + red[1] + red[2] + red[3];
  q = red[4] + red[5] + red[6] + red[7];
  const float mean = s * (1.0f / 1024.0f);
  const float var = q * (1.0f / 1024.0f) - mean * mean;
  const float rstd = rsqrtf(var + 1e-5f);
  float4 scv = ((const float4*)sc)[t];
  float4 shv = ((const float4*)sh)[t];
  uint2 p;
  p.x = pk2(scv.x * (v.x - mean) * rstd + shv.x, scv.y * (v.y - mean) * rstd + shv.y);
  p.y = pk2(scv.z * (v.z - mean) * rstd + shv.z, scv.w * (v.w - mean) * rstd + shv.w);
  ((uint2*)out)[(size_t)row * 256 + t] = p;
}

__global__ __launch_bounds__(256) void ln_kernel(
    const float* __restrict__ x, const float* __restrict__ sc,
    const float* __restrict__ sh, unsigned short* __restrict__ out)
{
  ln_row(x, sc, sh, out, blockIdx.x, threadIdx.x);
}

// ---------------------------------------------------------------------------
// Fused launch: blocks [0,4096) do ln1 rows; blocks >= 4096 grid-stride the
// fp32->bf16 weight conversion (wq gets 0.125*log2e folded in).
// ---------------------------------------------------------------------------
__global__ __launch_bounds__(256) void cvt_ln1(
    const float* __restrict__ wq, const float* __restrict__ wk,
    const float* __restrict__ wv, const float* __restrict__ wo,
    const float* __restrict__ w1, const float* __restrict__ w2,
    unsigned short* __restrict__ dst,
    const float* __restrict__ x, const float* __restrict__ ln1s,
    const float* __restrict__ ln1b, unsigned short* __restrict__ lnb)
{
  if (blockIdx.x < 4096) {
    ln_row(x, ln1s, ln1b, lnb, blockIdx.x, threadIdx.x);
    return;
  }
  const int M1 = 1 << 20;
  const int n4 = (12 * M1) / 4;
  const int stride = (gridDim.x - 4096) * 256;
  for (int i4 = (blockIdx.x - 4096) * 256 + threadIdx.x; i4 < n4; i4 += stride) {
    const size_t i = (size_t)i4 * 4;
    const int mi = (int)(i >> 20);
    const float* src;
    size_t off;
    float sc = 1.0f;
    if (mi < 4) {
      src = mi == 0 ? wq : mi == 1 ? wk : mi == 2 ? wv : wo;
      off = i & (size_t)(M1 - 1);
      if (mi == 0) sc = 0.125f * 1.44269504088896f;
    } else if (mi < 8) {
      src = w1; off = i - (size_t)4 * M1;
    } else {
      src = w2; off = i - (size_t)8 * M1;
    }
    float4 v = *(const float4*)(src + off);
    uint2 pq;
    pq.x = pk2(v.x * sc, v.y * sc);
    pq.y = pk2(v.z * sc, v.w * sc);
    ((uint2*)dst)[i4] = pq;
  }
}

// ---------------------------------------------------------------------------
extern "C" void kernel_launch(void* const* d_in, const int* in_sizes, int n_in,
                              void* d_out, int out_size, void* d_ws, size_t ws_size,
                              hipStream_t stream)
{
  const float* x    = (const float*)d_in[0];
  const float* wq   = (const float*)d_in[1];
  const float* wk   = (const float*)d_in[2];
  const float* wv   = (const float*)d_in[3];
  const float* wo   = (const float*)d_in[4];
  const float* bo   = (const float*)d_in[5];
  const float* ln1s = (const float*)d_in[6];
  const float* ln1b = (const float*)d_in[7];
  const float* ln2s = (const float*)d_in[8];
  const float* ln2b = (const float*)d_in[9];
  const float* w1   = (const float*)d_in[10];
  const float* b1   = (const float*)d_in[11];
  const float* w2   = (const float*)d_in[12];
  const float* b2   = (const float*)d_in[13];
  float* out = (float*)d_out;

  const int M = 4096; // B*S

  // workspace (~80 MB)
  unsigned short* ws   = (unsigned short*)d_ws;
  unsigned short* lnb  = ws;                              // [4096,1024]
  unsigned short* qkvw = lnb  + (size_t)4096 * 1024;      // [3072,1024]
  unsigned short* wob  = qkvw + (size_t)3072 * 1024;      // [1024,1024]
  unsigned short* w1b  = wob  + (size_t)1024 * 1024;      // [4096,1024]
  unsigned short* w2b  = w1b  + (size_t)4096 * 1024;      // [1024,4096]
  unsigned short* qkb  = w2b  + (size_t)4096 * 1024;      // [4096,2048] q|k; y1
  unsigned short* vtb  = qkb  + (size_t)4096 * 2048;      // [32,64,2048] V^T
  unsigned short* ctxb = vtb  + (size_t)32 * 64 * 2048;   // [4096,1024]
  float* hf = (float*)(ctxb + (size_t)4096 * 1024);       // [4096,1024] fp32

  // fused: ln1 = LN(x)  +  all weight fp32->bf16 conversions
  cvt_ln1<<<4096 + 2048, 256, 0, stream>>>(
      wq, wk, wv, wo, w1, w2, qkvw, x, ln1s, ln1b, lnb);
  // q|k -> qkb (stride 2048), v -> vtb transposed   [128^2 m97, 768 blocks]
  gemm_bt128<false, false, false, true, true><<<768, 256, 0, stream>>>(
      lnb, qkvw, nullptr, nullptr, qkb, M, 3072, 1024, 2048, vtb, 32);
  // ctx = causal_attention(q,k,v)   [split-KV, fixed-scale softmax]
  attn_kernel<<<1024, 256, 0, stream>>>(qkb, vtb, ctxb);
  // h = x + ctx @ wo^T + bo   (fp32)   [64x128 tiles BK=64]
  gemm_bt64<true, false, true, false><<<512, 256, 0, stream>>>(
      ctxb, wob, bo, x, hf, M, 1024, 1024, 1024);
  // ln2 = LN(h)
  ln_kernel<<<M, 256, 0, stream>>>(hf, ln2s, ln2b, lnb);
  // y1 = relu(ln2 @ w1^T + b1)   [128^2 m97, 1024 blocks]
  gemm_bt128<true, true, false, true, false><<<1024, 256, 0, stream>>>(
      lnb, w1b, b1, nullptr, qkb, M, 4096, 1024, 4096, nullptr, 32);
  // out = h + y1 @ w2^T + b2   [64x128 tiles BK=64]
  gemm_bt64<true, false, true, false><<<512, 256, 0, stream>>>(
      qkb, w2b, b2, hf, out, M, 1024, 4096, 1024);
}